// Round 11
// baseline (193.855 us; speedup 1.0000x reference)
//
#include <hip/hip_runtime.h>
#include <hip/hip_bf16.h>
#include <string.h>

// CrossOp via bf16 MFMA (32x32x16) implicit-GEMM.
// Block = (b, h): one output row, 128 px, all 64 co. Grid 512, 8 waves (512 thr).
// Wave w: co-half (w&1)*32, px-group (w>>1)*32. 9 MFMA k-steps (K=144).
// 2-deep load pipeline, ONE register set (write-then-reissue):
//   iter s: ds_write sr (=y(s+1), loaded iter s-1)  <- counted vmcnt skips stores
//           reissue sr <- y(s+2); MFMA on y_s; BARRIER; leaky + PLAIN stores.
// Stores go through L2 (no NT): full-line write-back, matches fillBuffer's
// 6.7 TB/s path. Barrier moved BEFORE the store burst (LDS hazards only need
// it after the ds_read phase) so stores overlap the next iteration.
// LDS: [3 rows][130 cols][16 ci pad->24] bf16, double-buffered (37.4 KB).

typedef __attribute__((ext_vector_type(8))) short short8;
typedef __attribute__((ext_vector_type(16))) float f32x16;
typedef __attribute__((ext_vector_type(2))) unsigned int u32x2;
typedef __attribute__((ext_vector_type(4))) unsigned int u32x4;

#define NEG_SLOPE 0.01f

constexpr int CIP   = 24;              // shorts per (row,col) ci slab (48 B)
constexpr int COLS  = 130;             // 128 + 2 halo
constexpr int ROWP  = COLS * CIP;      // 3120 shorts
constexpr int BUFSH = 3 * ROWP;        // 9360 shorts = 18.7 KB per buffer

__device__ __forceinline__ short to_bf16s(float f) {
    unsigned u = __builtin_bit_cast(unsigned, f);
    u += 0x7fffu + ((u >> 16) & 1u);   // RNE
    return (short)(u >> 16);
}

__device__ __forceinline__ unsigned pack2(float a, float b) {
    __hip_bfloat162 t = __float22bfloat162_rn(float2{a, b});   // v_cvt_pk_bf16_f32
    unsigned u;
    memcpy(&u, &t, sizeof(u));
    return u;
}

__global__ __launch_bounds__(512, 4)
void crossop_mfma32(const float* __restrict__ xp, const float* __restrict__ yp,
                    const float* __restrict__ wp, const float* __restrict__ bp,
                    float* __restrict__ out)
{
    __shared__ __align__(16) short st[2][BUFSH];

    const int bid     = blockIdx.x;                     // 0..511
    const int logical = ((bid & 7) << 6) | (bid >> 3);  // XCD-chunked swizzle
    const int b       = logical >> 7;
    const int h       = logical & 127;

    const int tid  = threadIdx.x;
    const int lane = tid & 63;
    const int wid  = tid >> 6;             // 0..7
    const int l31  = lane & 31;
    const int hi   = lane >> 5;            // k-half / +4 co rows
    const int co0w = (wid & 1) << 5;       // wave's co base (0 or 32)
    const int pxg  = wid >> 1;             // wave's px-group (0..3)

    float* ntgt  = out;
    float* inter = out + (size_t)4 * 64 * 16384;
    const float* ybase = yp + (size_t)b * 32 * 16 * 16384;

    // ---------------- zero LDS once (halo cols 0,129 + OOB rows stay 0) ---
    {
        u32x4 zz = {0, 0, 0, 0};
        u32x4* z = (u32x4*)&st[0][0];
        for (int i = tid; i < (2 * BUFSH * 2) / 16; i += 512) z[i] = zz;
    }

    // ---------------- staging mapping: 512 threads, 12 values each --------
    const int ch = tid >> 7;               // ci quarter (0..3) -> ci 4*ch..4*ch+3
    const int wv = tid & 127;              // input col w = wv, LDS col wv+1
    float sr[3][4];

#define STAGE_ISSUE(SRC) do {                                                 \
    const float* _s = (SRC);                                                  \
    _Pragma("unroll")                                                         \
    for (int it = 0; it < 3; ++it) {                                          \
        int hh = h + it - 1;                                                  \
        bool v = (unsigned)hh < 128u;                                         \
        const float* p = _s + (ptrdiff_t)(ch * 4) * 16384                     \
                            + (ptrdiff_t)hh * 128 + wv;                       \
        _Pragma("unroll")                                                     \
        for (int c = 0; c < 4; ++c)                                           \
            sr[it][c] = v ? p[(ptrdiff_t)c * 16384] : 0.f;                    \
    } } while (0)

#define STAGE_WRITE(BUF) do {                                                 \
    _Pragma("unroll")                                                         \
    for (int it = 0; it < 3; ++it) {                                          \
        if ((unsigned)(h + it - 1) < 128u) {                                  \
            u32x2 vv;                                                         \
            vv[0] = pack2(sr[it][0], sr[it][1]);                              \
            vv[1] = pack2(sr[it][2], sr[it][3]);                              \
            *(u32x2*)&(BUF)[it * ROWP + (wv + 1) * CIP + ch * 4] = vv;        \
        }                                                                     \
    } } while (0)

    // ---------------- persistent wy fragments (9 x short8 = 36 VGPR) ------
    short8 wy[9];
    #pragma unroll
    for (int sh = 0; sh < 9; ++sh) {
        #pragma unroll
        for (int j = 0; j < 8; ++j) {
            int ci = hi * 8 + j;           // k = (lane>>5)*8 + j within k-step
            wy[sh][j] = to_bf16s(wp[((co0w + l31) * 32 + 16 + ci) * 9 + sh]);
        }
    }

    // per-lane B column base (shorts) for this wave's px group
    const int cb = (pxg * 32 + l31) * CIP + hi * 8;

    // ---------------- prologue: x -> buf0; ox = conv_x + bias -------------
    STAGE_ISSUE(xp + (size_t)b * 16 * 16384);
    STAGE_WRITE(st[0]);
    __syncthreads();

    f32x16 ox;
    #pragma unroll
    for (int r = 0; r < 16; ++r)
        ox[r] = bp[co0w + (r & 3) + 8 * (r >> 2) + 4 * hi];
    {
        const short* sb = st[0];
        #pragma unroll
        for (int sh = 0; sh < 9; ++sh) {
            short8 ax;
            #pragma unroll
            for (int j = 0; j < 8; ++j) {
                int ci = hi * 8 + j;
                ax[j] = to_bf16s(wp[((co0w + l31) * 32 + ci) * 9 + sh]);
            }
            const int off = (sh / 3) * ROWP + (sh % 3) * CIP;
            ox = __builtin_amdgcn_mfma_f32_32x32x16_bf16(ax, *(const short8*)&sb[cb + off], ox, 0, 0, 0);
        }
    }

    // y0 -> buf1 (full-latency write, prologue only), then prefetch y1 -> sr
    STAGE_ISSUE(ybase + (size_t)0 * 16 * 16384);
    STAGE_WRITE(st[1]);
    STAGE_ISSUE(ybase + (size_t)1 * 16 * 16384);
    __syncthreads();

    // ---------------- s-loop: write-then-reissue 2-deep pipeline -----------
    f32x16 ms;
    #pragma unroll
    for (int r = 0; r < 16; ++r) ms[r] = 0.f;

    for (int s = 0; s < 32; ++s) {
        // 1) ds_write sr (= y(s+1), loaded last iteration): counted vmcnt
        //    (loads are older than last iter's stores -> stores stay in flight)
        if (s + 1 < 32) STAGE_WRITE(st[s & 1]);

        // 2) reissue the SAME sr registers with y(s+2) loads
        if (s + 2 < 32) STAGE_ISSUE(ybase + (size_t)(s + 2) * 16 * 16384);

        // 3) MFMA phase on y_s (st[(s+1)&1])
        const short* sb = st[(s + 1) & 1];
        f32x16 acc = ox;
        #pragma unroll
        for (int sh = 0; sh < 9; ++sh) {
            const int off = (sh / 3) * ROWP + (sh % 3) * CIP;
            acc = __builtin_amdgcn_mfma_f32_32x32x16_bf16(wy[sh], *(const short8*)&sb[cb + off], acc, 0, 0, 0);
        }

        // 4) barrier BEFORE the store burst: both LDS hazards (prev reads ->
        //    this writes; this writes -> next reads) are behind us now.
        asm volatile("s_waitcnt lgkmcnt(0)" ::: "memory");
        __builtin_amdgcn_s_barrier();
        asm volatile("" ::: "memory");

        // 5) leaky + PLAIN stores (L2 write-back path), overlap next iter
        {
            float* p0 = inter + ((size_t)(b * 32 + s) * 64 + co0w + 4 * hi) * 16384
                      + (size_t)h * 128 + pxg * 32 + l31;
            #pragma unroll
            for (int r = 0; r < 16; ++r) {
                float v = acc[r];
                v = v >= 0.f ? v : NEG_SLOPE * v;
                p0[(ptrdiff_t)((r & 3) + 8 * (r >> 2)) * 16384] = v;
                ms[r] += v;
            }
        }
    }

    // ---------------- mean over Sy ----------------------------------------
    {
        float* p0 = ntgt + ((size_t)b * 64 + co0w + 4 * hi) * 16384
                  + (size_t)h * 128 + pxg * 32 + l31;
        #pragma unroll
        for (int r = 0; r < 16; ++r)
            p0[(ptrdiff_t)((r & 3) + 8 * (r >> 2)) * 16384] = ms[r] * 0.03125f;
    }
#undef STAGE_ISSUE
#undef STAGE_WRITE
}

extern "C" void kernel_launch(void* const* d_in, const int* in_sizes, int n_in,
                              void* d_out, int out_size, void* d_ws, size_t ws_size,
                              hipStream_t stream) {
    const float* x    = (const float*)d_in[0];
    const float* y    = (const float*)d_in[1];
    const float* wgt  = (const float*)d_in[2];
    const float* bias = (const float*)d_in[3];
    float* out = (float*)d_out;

    crossop_mfma32<<<512, 512, 0, stream>>>(x, y, wgt, bias, out);
}

// Round 12
// 156.827 us; speedup vs baseline: 1.2361x; 1.2361x over previous
//
#include <hip/hip_runtime.h>
#include <hip/hip_bf16.h>
#include <string.h>

// CrossOp via bf16 MFMA (32x32x16) implicit-GEMM.
// Block = (b, h): one output row, 128 px, all 64 co. Grid 512, 8 waves (512 thr).
// Wave w: co-half (w&1)*32, px-group (w>>1)*32. 9 MFMA k-steps (K=144).
// 4-buffer LDS rotation, barrier every 2 iterations:
//   iter s: ds_write sr -> st[(s+2)&3] (y(s+2), loaded iter s-1; counted vmcnt
//           leaves NT stores in flight), reissue sr <- y(s+3), MFMA on st[s&3],
//           leaky + NT stores; s_barrier only on odd s (skew < 2 iters, and all
//           same-buffer dependencies are 2 iters apart with a barrier between).
// LDS: 4 x [3 rows][130 cols][16 ci pad->24] bf16 = 74.9 KB (2 blocks/CU).

typedef __attribute__((ext_vector_type(8))) short short8;
typedef __attribute__((ext_vector_type(16))) float f32x16;
typedef __attribute__((ext_vector_type(2))) unsigned int u32x2;
typedef __attribute__((ext_vector_type(4))) unsigned int u32x4;

#define NEG_SLOPE 0.01f

constexpr int CIP   = 24;              // shorts per (row,col) ci slab (48 B)
constexpr int COLS  = 130;             // 128 + 2 halo
constexpr int ROWP  = COLS * CIP;      // 3120 shorts
constexpr int BUFSH = 3 * ROWP;        // 9360 shorts = 18.7 KB per buffer

__device__ __forceinline__ short to_bf16s(float f) {
    unsigned u = __builtin_bit_cast(unsigned, f);
    u += 0x7fffu + ((u >> 16) & 1u);   // RNE
    return (short)(u >> 16);
}

__device__ __forceinline__ unsigned pack2(float a, float b) {
    __hip_bfloat162 t = __float22bfloat162_rn(float2{a, b});   // v_cvt_pk_bf16_f32
    unsigned u;
    memcpy(&u, &t, sizeof(u));
    return u;
}

__global__ __launch_bounds__(512, 4)
void crossop_mfma32(const float* __restrict__ xp, const float* __restrict__ yp,
                    const float* __restrict__ wp, const float* __restrict__ bp,
                    float* __restrict__ out)
{
    __shared__ __align__(16) short st[4][BUFSH];

    const int bid     = blockIdx.x;                     // 0..511
    const int logical = ((bid & 7) << 6) | (bid >> 3);  // XCD-chunked swizzle
    const int b       = logical >> 7;
    const int h       = logical & 127;

    const int tid  = threadIdx.x;
    const int lane = tid & 63;
    const int wid  = tid >> 6;             // 0..7
    const int l31  = lane & 31;
    const int hi   = lane >> 5;            // k-half / +4 co rows
    const int co0w = (wid & 1) << 5;       // wave's co base (0 or 32)
    const int pxg  = wid >> 1;             // wave's px-group (0..3)

    float* ntgt  = out;
    float* inter = out + (size_t)4 * 64 * 16384;
    const float* ybase = yp + (size_t)b * 32 * 16 * 16384;

    // ---------------- zero LDS once (halo cols 0,129 + OOB rows stay 0) ---
    {
        u32x4 zz = {0, 0, 0, 0};
        u32x4* z = (u32x4*)&st[0][0];
        for (int i = tid; i < (4 * BUFSH * 2) / 16; i += 512) z[i] = zz;
    }

    // ---------------- staging mapping: 512 threads, 12 values each --------
    const int ch = tid >> 7;               // ci quarter (0..3) -> ci 4*ch..4*ch+3
    const int wv = tid & 127;              // input col w = wv, LDS col wv+1
    float sr[3][4];

#define STAGE_ISSUE(SRC) do {                                                 \
    const float* _s = (SRC);                                                  \
    _Pragma("unroll")                                                         \
    for (int it = 0; it < 3; ++it) {                                          \
        int hh = h + it - 1;                                                  \
        bool v = (unsigned)hh < 128u;                                         \
        const float* p = _s + (ptrdiff_t)(ch * 4) * 16384                     \
                            + (ptrdiff_t)hh * 128 + wv;                       \
        _Pragma("unroll")                                                     \
        for (int c = 0; c < 4; ++c)                                           \
            sr[it][c] = v ? p[(ptrdiff_t)c * 16384] : 0.f;                    \
    } } while (0)

#define STAGE_WRITE(BUF) do {                                                 \
    _Pragma("unroll")                                                         \
    for (int it = 0; it < 3; ++it) {                                          \
        if ((unsigned)(h + it - 1) < 128u) {                                  \
            u32x2 vv;                                                         \
            vv[0] = pack2(sr[it][0], sr[it][1]);                              \
            vv[1] = pack2(sr[it][2], sr[it][3]);                              \
            *(u32x2*)&(BUF)[it * ROWP + (wv + 1) * CIP + ch * 4] = vv;        \
        }                                                                     \
    } } while (0)

    // ---------------- persistent wy fragments (9 x short8 = 36 VGPR) ------
    short8 wy[9];
    #pragma unroll
    for (int sh = 0; sh < 9; ++sh) {
        #pragma unroll
        for (int j = 0; j < 8; ++j) {
            int ci = hi * 8 + j;           // k = (lane>>5)*8 + j within k-step
            wy[sh][j] = to_bf16s(wp[((co0w + l31) * 32 + 16 + ci) * 9 + sh]);
        }
    }

    // per-lane B column base (shorts) for this wave's px group
    const int cb = (pxg * 32 + l31) * CIP + hi * 8;

    // ---------------- prologue ---------------------------------------------
    // x -> st[2] (s=0 overwrites st[2] with y2 only AFTER the final sync);
    // ox = conv_x + bias; then y0 -> st[0], y1 -> st[1], y2 -> sr.
    STAGE_ISSUE(xp + (size_t)b * 16 * 16384);
    STAGE_WRITE(st[2]);
    __syncthreads();

    f32x16 ox;
    #pragma unroll
    for (int r = 0; r < 16; ++r)
        ox[r] = bp[co0w + (r & 3) + 8 * (r >> 2) + 4 * hi];
    {
        const short* sb = st[2];
        #pragma unroll
        for (int sh = 0; sh < 9; ++sh) {
            short8 ax;
            #pragma unroll
            for (int j = 0; j < 8; ++j) {
                int ci = hi * 8 + j;
                ax[j] = to_bf16s(wp[((co0w + l31) * 32 + ci) * 9 + sh]);
            }
            const int off = (sh / 3) * ROWP + (sh % 3) * CIP;
            ox = __builtin_amdgcn_mfma_f32_32x32x16_bf16(ax, *(const short8*)&sb[cb + off], ox, 0, 0, 0);
        }
    }

    STAGE_ISSUE(ybase + (size_t)0 * 16 * 16384);
    STAGE_WRITE(st[0]);
    STAGE_ISSUE(ybase + (size_t)1 * 16 * 16384);
    STAGE_WRITE(st[1]);
    STAGE_ISSUE(ybase + (size_t)2 * 16 * 16384);
    __syncthreads();

    // ---------------- s-loop: 4-buffer rotation, barrier every 2 iters -----
    f32x16 ms;
    #pragma unroll
    for (int r = 0; r < 16; ++r) ms[r] = 0.f;

    for (int s = 0; s < 32; ++s) {
        // 1) ds_write sr (= y(s+2), loaded last iteration): counted vmcnt
        //    (these loads are older than last iter's NT stores)
        if (s + 2 < 32) STAGE_WRITE(st[(s + 2) & 3]);

        // 2) reissue the SAME sr registers with y(s+3) loads
        if (s + 3 < 32) STAGE_ISSUE(ybase + (size_t)(s + 3) * 16 * 16384);

        // 3) MFMA phase on y_s (st[s&3])
        const short* sb = st[s & 3];
        f32x16 acc = ox;
        #pragma unroll
        for (int sh = 0; sh < 9; ++sh) {
            const int off = (sh / 3) * ROWP + (sh % 3) * CIP;
            acc = __builtin_amdgcn_mfma_f32_32x32x16_bf16(wy[sh], *(const short8*)&sb[cb + off], acc, 0, 0, 0);
        }

        // 4) leaky + NT stores (no-allocate path; never drained in the loop)
        {
            float* p0 = inter + ((size_t)(b * 32 + s) * 64 + co0w + 4 * hi) * 16384
                      + (size_t)h * 128 + pxg * 32 + l31;
            #pragma unroll
            for (int r = 0; r < 16; ++r) {
                float v = acc[r];
                v = v >= 0.f ? v : NEG_SLOPE * v;
                __builtin_nontemporal_store(v, p0 + (ptrdiff_t)((r & 3) + 8 * (r >> 2)) * 16384);
                ms[r] += v;
            }
        }

        // 5) barrier every SECOND iteration (all same-buffer deps are 2 apart)
        if (s & 1) {
            asm volatile("s_waitcnt lgkmcnt(0)" ::: "memory");
            __builtin_amdgcn_s_barrier();
            asm volatile("" ::: "memory");
        }
    }

    // ---------------- mean over Sy ----------------------------------------
    {
        float* p0 = ntgt + ((size_t)b * 64 + co0w + 4 * hi) * 16384
                  + (size_t)h * 128 + pxg * 32 + l31;
        #pragma unroll
        for (int r = 0; r < 16; ++r)
            __builtin_nontemporal_store(ms[r] * 0.03125f,
                                        p0 + (ptrdiff_t)((r & 3) + 8 * (r >> 2)) * 16384);
    }
#undef STAGE_ISSUE
#undef STAGE_WRITE
}

extern "C" void kernel_launch(void* const* d_in, const int* in_sizes, int n_in,
                              void* d_out, int out_size, void* d_ws, size_t ws_size,
                              hipStream_t stream) {
    const float* x    = (const float*)d_in[0];
    const float* y    = (const float*)d_in[1];
    const float* wgt  = (const float*)d_in[2];
    const float* bias = (const float*)d_in[3];
    float* out = (float*)d_out;

    crossop_mfma32<<<512, 512, 0, stream>>>(x, y, wgt, bias, out);
}

// Round 13
// 141.891 us; speedup vs baseline: 1.3662x; 1.1053x over previous
//
#include <hip/hip_runtime.h>
#include <hip/hip_bf16.h>
#include <string.h>

// CrossOp via bf16 MFMA (32x32x16) implicit-GEMM, 2-row h-band blocks.
// Block = (b, hb): TWO output rows (h = hb*2, hb*2+1) x 128 px x 64 co.
// Grid 256 = 1 block/CU. 1024 threads = 16 waves:
//   wave w: co-half (w&1)*32, hh = (w>>1)&1, w-quad = w>>2 (32 px).
// Per iteration the block writes 2h x 128w x 64co: per co-plane 1 KB
// CONTIGUOUS and simultaneous (vs 512B before) -> better DRAM page efficiency.
// Pipeline identical to round-10: write-then-reissue depth-2, counted vmcnt
// (NT stores never drained in-loop), lgkm-only barrier.
// LDS: y dbuf 2 x [4 rows][130 cols][16ci pad->24] + static x tile = 74.9 KB.

typedef __attribute__((ext_vector_type(8))) short short8;
typedef __attribute__((ext_vector_type(16))) float f32x16;
typedef __attribute__((ext_vector_type(4))) unsigned int u32x4;

#define NEG_SLOPE 0.01f

constexpr int CIP    = 24;             // shorts per (row,col) ci slab (48 B)
constexpr int COLS   = 130;            // 128 + 2 halo (halo cols stay zero)
constexpr int ROWP   = COLS * CIP;     // 3120 shorts
constexpr int TILESH = 4 * ROWP;       // 12480 shorts = 24.96 KB per tile

__device__ __forceinline__ short to_bf16s(float f) {
    unsigned u = __builtin_bit_cast(unsigned, f);
    u += 0x7fffu + ((u >> 16) & 1u);   // RNE
    return (short)(u >> 16);
}

__device__ __forceinline__ unsigned pack2(float a, float b) {
    __hip_bfloat162 t = __float22bfloat162_rn(float2{a, b});   // v_cvt_pk_bf16_f32
    unsigned u;
    memcpy(&u, &t, sizeof(u));
    return u;
}

__global__ __launch_bounds__(1024, 4)
void crossop_v4(const float* __restrict__ xp, const float* __restrict__ yp,
                const float* __restrict__ wp, const float* __restrict__ bp,
                float* __restrict__ out)
{
    __shared__ __align__(16) short st[3][TILESH];   // [0],[1]=y dbuf, [2]=x static

    const int bid     = blockIdx.x;                     // 0..255
    const int logical = ((bid & 7) << 5) | (bid >> 3);  // XCD-chunked swizzle
    const int b       = logical >> 6;                   // 0..3
    const int hb      = logical & 63;                   // 2-row band index

    const int tid  = threadIdx.x;
    const int lane = tid & 63;
    const int wid  = tid >> 6;             // 0..15
    const int l31  = lane & 31;
    const int hi   = lane >> 5;            // k-half / +4 co rows
    const int co0w = (wid & 1) << 5;       // wave's co base (0 or 32)
    const int pxg  = wid >> 1;             // 0..7
    const int hh   = pxg & 1;              // which of the 2 output rows
    const int wq   = pxg >> 1;             // w-quad (0..3), 32 px

    float* ntgt  = out;
    float* inter = out + (size_t)4 * 64 * 16384;
    const float* ybase = yp + (size_t)b * 32 * 16 * 16384;

    // ---------------- zero LDS once (halo cols / OOB rows stay 0) ---------
    {
        u32x4 zz = {0, 0, 0, 0};
        u32x4* z = (u32x4*)&st[0][0];
        for (int i = tid; i < (3 * TILESH * 2) / 16; i += 1024) z[i] = zz;
    }

    // ---------------- staging: 1024 threads, 8 values each -----------------
    const int  wv   = tid & 127;           // input col / tile col wv+1
    const int  ch   = tid >> 7;            // 0..7
    const int  rr   = ch >> 1;             // tile row 0..3 (input row hb*2-1+rr)
    const int  cih  = ch & 1;              // ci half
    const int  hin  = hb * 2 - 1 + rr;
    const bool sval = (unsigned)hin < 128u;
    float sr[8];

#define STAGE_ISSUE(SRC) do {                                                 \
    const float* p = (SRC) + (ptrdiff_t)(cih * 8) * 16384                     \
                            + (ptrdiff_t)hin * 128 + wv;                      \
    _Pragma("unroll")                                                         \
    for (int c = 0; c < 8; ++c)                                               \
        sr[c] = sval ? p[(ptrdiff_t)c * 16384] : 0.f;                         \
    } while (0)

#define STAGE_WRITE(BUF) do { if (sval) {                                     \
    u32x4 vv;                                                                 \
    _Pragma("unroll")                                                         \
    for (int c2 = 0; c2 < 4; ++c2)                                            \
        vv[c2] = pack2(sr[2 * c2], sr[2 * c2 + 1]);                           \
    *(u32x4*)&(BUF)[rr * ROWP + (wv + 1) * CIP + cih * 8] = vv;               \
    } } while (0)

    // ---------------- persistent wy fragments (9 x short8 = 36 VGPR) ------
    short8 wy[9];
    #pragma unroll
    for (int sh = 0; sh < 9; ++sh) {
        #pragma unroll
        for (int j = 0; j < 8; ++j) {
            int ci = hi * 8 + j;           // k = (lane>>5)*8 + j within k-step
            wy[sh][j] = to_bf16s(wp[((co0w + l31) * 32 + 16 + ci) * 9 + sh]);
        }
    }

    // per-lane B column base; output px p reads tile cols p..p+2, rows hh+kh
    const int cb = (wq * 32 + l31) * CIP + hi * 8;

    // ---------------- prologue: x -> st[2]; ox = conv_x + bias -------------
    STAGE_ISSUE(xp + (size_t)b * 16 * 16384);
    STAGE_WRITE(st[2]);
    __syncthreads();

    f32x16 ox;
    #pragma unroll
    for (int r = 0; r < 16; ++r)
        ox[r] = bp[co0w + (r & 3) + 8 * (r >> 2) + 4 * hi];
    {
        const short* sb = st[2];
        #pragma unroll
        for (int sh = 0; sh < 9; ++sh) {
            short8 ax;
            #pragma unroll
            for (int j = 0; j < 8; ++j) {
                int ci = hi * 8 + j;
                ax[j] = to_bf16s(wp[((co0w + l31) * 32 + ci) * 9 + sh]);
            }
            const int off = (sh / 3 + hh) * ROWP + (sh % 3) * CIP;
            ox = __builtin_amdgcn_mfma_f32_32x32x16_bf16(ax, *(const short8*)&sb[cb + off], ox, 0, 0, 0);
        }
    }

    // y0 -> st[1] (full-latency, prologue only), then prefetch y1 -> sr
    STAGE_ISSUE(ybase + (size_t)0 * 16 * 16384);
    STAGE_WRITE(st[1]);
    STAGE_ISSUE(ybase + (size_t)1 * 16 * 16384);
    __syncthreads();

    // ---------------- s-loop: write-then-reissue depth-2 pipeline ----------
    f32x16 ms;
    #pragma unroll
    for (int r = 0; r < 16; ++r) ms[r] = 0.f;

    for (int s = 0; s < 32; ++s) {
        // 1) ds_write sr (= y(s+1)): counted vmcnt, NT stores stay in flight
        if (s + 1 < 32) STAGE_WRITE(st[s & 1]);

        // 2) reissue the SAME sr registers with y(s+2) loads
        if (s + 2 < 32) STAGE_ISSUE(ybase + (size_t)(s + 2) * 16 * 16384);

        // 3) MFMA phase on y_s (st[(s+1)&1])
        const short* sb = st[(s + 1) & 1];
        f32x16 acc = ox;
        #pragma unroll
        for (int sh = 0; sh < 9; ++sh) {
            const int off = (sh / 3 + hh) * ROWP + (sh % 3) * CIP;
            acc = __builtin_amdgcn_mfma_f32_32x32x16_bf16(wy[sh], *(const short8*)&sb[cb + off], acc, 0, 0, 0);
        }

        // 4) leaky + NT stores: block writes 1 KB contiguous per co-plane
        {
            float* p0 = inter + ((size_t)(b * 32 + s) * 64 + co0w + 4 * hi) * 16384
                      + (size_t)(hb * 2 + hh) * 128 + wq * 32 + l31;
            #pragma unroll
            for (int r = 0; r < 16; ++r) {
                float v = acc[r];
                v = v >= 0.f ? v : NEG_SLOPE * v;
                __builtin_nontemporal_store(v, p0 + (ptrdiff_t)((r & 3) + 8 * (r >> 2)) * 16384);
                ms[r] += v;
            }
        }

        // 5) LDS-only barrier
        asm volatile("s_waitcnt lgkmcnt(0)" ::: "memory");
        __builtin_amdgcn_s_barrier();
        asm volatile("" ::: "memory");
    }

    // ---------------- mean over Sy ----------------------------------------
    {
        float* p0 = ntgt + ((size_t)b * 64 + co0w + 4 * hi) * 16384
                  + (size_t)(hb * 2 + hh) * 128 + wq * 32 + l31;
        #pragma unroll
        for (int r = 0; r < 16; ++r)
            __builtin_nontemporal_store(ms[r] * 0.03125f,
                                        p0 + (ptrdiff_t)((r & 3) + 8 * (r >> 2)) * 16384);
    }
#undef STAGE_ISSUE
#undef STAGE_WRITE
}

extern "C" void kernel_launch(void* const* d_in, const int* in_sizes, int n_in,
                              void* d_out, int out_size, void* d_ws, size_t ws_size,
                              hipStream_t stream) {
    const float* x    = (const float*)d_in[0];
    const float* y    = (const float*)d_in[1];
    const float* wgt  = (const float*)d_in[2];
    const float* bias = (const float*)d_in[3];
    float* out = (float*)d_out;

    crossop_v4<<<256, 1024, 0, stream>>>(x, y, wgt, bias, out);
}